// Round 11
// baseline (301.273 us; speedup 1.0000x reference)
//
#include <hip/hip_runtime.h>

#define V 255
#define L 16
#define E (V*L)      // 4080
#define P 8
#define CLIPV 10.0f

// tanh(0.5 * clip(s, -10, 10)) = 1 - 2/(exp(clip(s))+1)
__device__ __forceinline__ float tanh_half_clip(float s) {
    float t = fminf(fmaxf(s, -CLIPV), CLIPV);
    float e = __expf(t);
    return 1.0f - __fdividef(2.0f, e + 1.0f);
}

// 512-thread block = 2 independent scalar (b,p) units (half = tid>>8, wave-
// uniform). 34.7 KB LDS -> 4 blocks/CU = 32 waves/CU. Fused even+odd via
// cr(rc(i)) == i (r9 algebra): per edge the even output consumed by thread v
// is log((e+T)/(e-T+1e-9e)) with e = own zsub'd odd output, T = row total.
// Own e's are re-read from LDS (not held in regs) to keep VGPR <= ~72.
template <int MODE>
__global__ __launch_bounds__(512, 6) void bph_kernel(
    const float* __restrict__ x,
    const float* __restrict__ oddw_v,
    const float* __restrict__ oddw_e,
    const float* __restrict__ w_e_out,
    const int*   __restrict__ perma,
    const int*   __restrict__ rc_idx,
    const int*   __restrict__ cr_idx,
    float* __restrict__ eo_ws,     // MODE 0
    const int* __restrict__ invp,  // MODE 1
    float* __restrict__ out)       // MODE 1
{
    __shared__ float OO[2 * E];     // zsub'd odd outputs, [half][l][v] col-major
    __shared__ float TT[2 * 256];   // row totals per half

    const int tid  = threadIdx.x;
    const int half = tid >> 8;          // wave-uniform
    const int v    = tid & 255;
    const int unit = blockIdx.x * 2 + half;   // == b*P + p
    const int b = unit >> 3;
    const int p = unit & 7;
    const bool act = (v < V);
    const int obase = half * E;
    const int tbase = half * 256;

    float xv = 0.0f;
    int offc[L];   // OO element index for cr-gather (half folded in)
    int offt[L];   // TT element index for totals read (half folded in)
    if (act) {
        xv = x[b * (V + 1) + perma[p * (V + 1) + v + 1]];
        const int4* rc4 = (const int4*)(rc_idx + v * L);
        const int4* cr4 = (const int4*)(cr_idx + v * L);
#pragma unroll
        for (int i = 0; i < 4; ++i) {
            int4 a = rc4[i];
            int4 c = cr4[i];
            offc[4*i+0] = obase + (c.x & 15) * V + (c.x >> 4);
            offc[4*i+1] = obase + (c.y & 15) * V + (c.y >> 4);
            offc[4*i+2] = obase + (c.z & 15) * V + (c.z >> 4);
            offc[4*i+3] = obase + (c.w & 15) * V + (c.w >> 4);
            offt[4*i+0] = tbase + (a.x >> 4);
            offt[4*i+1] = tbase + (a.y >> 4);
            offt[4*i+2] = tbase + (a.z >> 4);
            offt[4*i+3] = tbase + (a.w >> 4);
        }
    }

    // ---- t=0 odd layer (message==0 -> rank-1), zsub'd, published ----
    if (act) {
#pragma unroll
        for (int m = 0; m < L; ++m) {
            float e = tanh_half_clip(xv * oddw_v[m]);    // uniform s_load
            OO[obase + m * V + v] = (e == 0.0f) ? 1.0f : e;
        }
    }
    __syncthreads();

    float ev[L];
#pragma unroll 1
    for (int t = 0; t < 5; ++t) {
        // ---- phase A: own column + cr-gather tree product -> row total ----
        if (act) {
#pragma unroll
            for (int m = 0; m < L; ++m) ev[m] = OO[obase + m * V + v];
            float t0 = 1.0f, t1 = 1.0f, t2 = 1.0f, t3 = 1.0f;
#pragma unroll
            for (int l = 0; l < L; l += 4) {
                t0 *= OO[offc[l + 0]];
                t1 *= OO[offc[l + 1]];
                t2 *= OO[offc[l + 2]];
                t3 *= OO[offc[l + 3]];
            }
            TT[tbase + v] = (t0 * t1) * (t2 * t3);
        }
        __syncthreads();

        // ---- phase F: totals in, fused logratio, odd matvec, publish ----
        // r = T/e; log((1+r)/(1-r+1e-9)+1e-9) == log((e+T)/(e-T+1e-9*e))
        // to ~1e-6; |r| <= tanh(5)^15 ~ 0.9986 so t=0 clip is an identity.
        if (act) {
#pragma unroll
            for (int l = 0; l < L; ++l) {
                float Tl = TT[offt[l]];
                float e  = ev[l];
                float num = e + Tl;
                float den = fmaf(e, 1e-9f, e - Tl);
                ev[l] = __logf(__fdividef(num, den));
            }
            if (t < 4) {
                const float* __restrict__ wv = oddw_v + (t + 1) * L;
                const float* __restrict__ wm = oddw_e + (t + 1) * (L * L);
#pragma unroll
                for (int mh = 0; mh < 2; ++mh) {           // 8-wide halves
                    float s[8];
#pragma unroll
                    for (int j = 0; j < 8; ++j)
                        s[j] = xv * wv[mh * 8 + j];        // uniform s_load
#pragma unroll
                    for (int l = 0; l < L; ++l) {
                        const float el = ev[l];
#pragma unroll
                        for (int j = 0; j < 8; ++j) {
                            const int m = mh * 8 + j;
                            if (m != l)                    // diag, compile-time
                                s[j] = fmaf(el, wm[l * L + m], s[j]);
                        }
                    }
#pragma unroll
                    for (int j = 0; j < 8; ++j) {
                        float e = tanh_half_clip(s[j]);
                        OO[obase + (mh * 8 + j) * V + v] =
                            (e == 0.0f) ? 1.0f : e;        // zsub'd publish
                    }
                }
            } else {
                // ---- final: dot with w_e_out from registers ----
                float d = 0.0f;
#pragma unroll
                for (int l = 0; l < L; ++l)
                    d = fmaf(ev[l], w_e_out[l], d);
                if (MODE == 0) {
                    eo_ws[(size_t)unit * V + v] = d;
                } else {
                    int j = invp[p * (V + 1) + (v + 1)];
                    atomicAdd(&out[b * (V + 1) + j], d);
                }
            }
        }
        if (t < 4) __syncthreads();   // uniform condition: allowed
    }
}

// gather-sum epilogue (MODE 0 path)
__global__ __launch_bounds__(256) void out_kernel(
    const float* __restrict__ x,
    const float* __restrict__ eo_ws,
    const int* __restrict__ perma,
    float* __restrict__ out)
{
    const int b = blockIdx.x;
    const int j = threadIdx.x;   // 0..255
    float acc = x[b * (V + 1) + j];
#pragma unroll
    for (int p = 0; p < P; ++p) {
        int idx = perma[p * (V + 1) + j];
        if (idx > 0) acc += eo_ws[((size_t)(b * P + p)) * V + (idx - 1)];
    }
    out[b * (V + 1) + j] = acc;
}

// fallback helpers (MODE 1 path)
__global__ __launch_bounds__(256) void inv_kernel(const int* __restrict__ perma,
                                                  int* __restrict__ invp)
{
    int p = blockIdx.x, j = threadIdx.x;
    invp[p * (V + 1) + perma[p * (V + 1) + j]] = j;
}

__global__ __launch_bounds__(256) void copy_kernel(const float* __restrict__ x,
                                                   float* __restrict__ out, int n)
{
    int i = blockIdx.x * 256 + threadIdx.x;
    if (i < n) out[i] = x[i];
}

extern "C" void kernel_launch(void* const* d_in, const int* in_sizes, int n_in,
                              void* d_out, int out_size, void* d_ws, size_t ws_size,
                              hipStream_t stream)
{
    const float* x       = (const float*)d_in[0];
    const float* oddw_v  = (const float*)d_in[2];
    const float* oddw_e  = (const float*)d_in[3];
    const float* w_e_out = (const float*)d_in[4];
    const int*   perma   = (const int*)d_in[5];
    const int*   rc      = (const int*)d_in[6];
    const int*   cr      = (const int*)d_in[7];
    float* out = (float*)d_out;

    const int Bx = in_sizes[0] / (V + 1);
    const int nunits = Bx * P;
    const int npairs = nunits / 2;
    const size_t need = (size_t)nunits * V * sizeof(float);

    if (ws_size >= need) {
        float* eo = (float*)d_ws;
        hipLaunchKernelGGL((bph_kernel<0>), dim3(npairs), dim3(512), 0, stream,
                           x, oddw_v, oddw_e, w_e_out, perma, rc, cr,
                           eo, (const int*)nullptr, (float*)nullptr);
        hipLaunchKernelGGL(out_kernel, dim3(Bx), dim3(256), 0, stream,
                           x, eo, perma, out);
    } else {
        // atomic fallback: needs P*(V+1)*4 = 8KB workspace for inverse perm
        int* invp = (int*)d_ws;
        hipLaunchKernelGGL(inv_kernel, dim3(P), dim3(V + 1), 0, stream, perma, invp);
        hipLaunchKernelGGL(copy_kernel, dim3((out_size + 255) / 256), dim3(256), 0, stream,
                           x, out, out_size);
        hipLaunchKernelGGL((bph_kernel<1>), dim3(npairs), dim3(512), 0, stream,
                           x, oddw_v, oddw_e, w_e_out, perma, rc, cr,
                           (float*)nullptr, invp, out);
    }
}

// Round 12
// 234.066 us; speedup vs baseline: 1.2871x; 1.2871x over previous
//
#include <hip/hip_runtime.h>

#define V 255
#define VS 256          // padded LDS column stride
#define L 16
#define P 8
#define CLIPV 10.0f

typedef __attribute__((ext_vector_type(2))) float f32x2;

__device__ __forceinline__ f32x2 splat(float a) { return (f32x2){a, a}; }
__device__ __forceinline__ f32x2 pk_fma(f32x2 a, f32x2 b, f32x2 c) {
    return __builtin_elementwise_fma(a, b, c);
}

// tanh(0.5 * clip(s, -10, 10)) = 1 - 2/(exp(clip(s))+1), per component
__device__ __forceinline__ f32x2 tanh_half_clip_pk(f32x2 s) {
    f32x2 t = __builtin_elementwise_min(
                  __builtin_elementwise_max(s, splat(-CLIPV)), splat(CLIPV));
    f32x2 r;
    float ex = __expf(t.x); r.x = 1.0f - __fdividef(2.0f, ex + 1.0f);
    float ey = __expf(t.y); r.y = 1.0f - __fdividef(2.0f, ey + 1.0f);
    return r;
}

// zero-substitution (reference: e += (|e|==0))
__device__ __forceinline__ f32x2 zsub(f32x2 o) {
    o.x = (o.x == 0.0f) ? 1.0f : o.x;
    o.y = (o.y == 0.0f) ? 1.0f : o.y;
    return o;
}

// r9 structure (fused even+odd via cr(rc(i))==i, f32x2 = 2 (b,p) units per
// thread), instruction-dieted:
//  - LDS padded to stride 256: thread 255 is a live dummy (writes col/slot
//    255, never gathered) -> NO exec-mask predication in the hot loop.
//  - t-loop fully unrolled -> compile-time weight offsets, s_load pipelining.
//  - shift-based LDS addressing.
template <int MODE>
__global__ __launch_bounds__(256, 4) void bpd_kernel(
    const float* __restrict__ x,
    const float* __restrict__ oddw_v,
    const float* __restrict__ oddw_e,
    const float* __restrict__ w_e_out,
    const int*   __restrict__ perma,
    const int*   __restrict__ rc_idx,
    const int*   __restrict__ cr_idx,
    float* __restrict__ eo_ws,     // MODE 0
    const int* __restrict__ invp,  // MODE 1
    float* __restrict__ out)       // MODE 1
{
    __shared__ f32x2 OO[L * VS];   // zsub'd odd outputs, col-major, 32 KB
    __shared__ f32x2 TOT[VS];      // per-row products, 2 KB

    const int tid = threadIdx.x;
    const int blk = blockIdx.x;        // pair id
    const int b  = blk >> 2;
    const int pA = (blk & 3) * 2;
    const int pB = pA + 1;
    const int v  = tid;                // 0..255; 255 = dummy (full duty)
    const int vi = (v < V) ? v : (V - 1);   // index-table row (dup for dummy)

    // x values (dummy thread reads a valid but unused pair)
    f32x2 xv;
    {
        const float* xrow = x + b * (V + 1);
        const int vc = (v < V) ? (v + 1) : V;
        xv.x = xrow[perma[pA * (V + 1) + vc]];
        xv.y = xrow[perma[pB * (V + 1) + vc]];
    }

    int offc[L];   // OO element index for cr-gather
    int offt[L];   // TOT element index
    {
        const int4* rc4 = (const int4*)(rc_idx + vi * L);
        const int4* cr4 = (const int4*)(cr_idx + vi * L);
#pragma unroll
        for (int i = 0; i < 4; ++i) {
            int4 a = rc4[i];
            int4 c = cr4[i];
            offc[4*i+0] = ((c.x & 15) << 8) | (c.x >> 4);
            offc[4*i+1] = ((c.y & 15) << 8) | (c.y >> 4);
            offc[4*i+2] = ((c.z & 15) << 8) | (c.z >> 4);
            offc[4*i+3] = ((c.w & 15) << 8) | (c.w >> 4);
            offt[4*i+0] = a.x >> 4;
            offt[4*i+1] = a.y >> 4;
            offt[4*i+2] = a.z >> 4;
            offt[4*i+3] = a.w >> 4;
        }
    }

    // ---- t=0 odd layer (message==0 -> rank-1), zsub'd ----
    f32x2 ev[L];
#pragma unroll
    for (int m = 0; m < L; ++m)
        ev[m] = zsub(tanh_half_clip_pk(xv * oddw_v[m]));   // uniform s_load

#pragma unroll
    for (int t = 0; t < 5; ++t) {
        // ---- publish e (conflict-free column writes) ----
#pragma unroll
        for (int m = 0; m < L; ++m) OO[(m << 8) + v] = ev[m];
        __syncthreads();

        // ---- cr-gather + tree product -> row total ----
        {
            f32x2 t0 = OO[offc[0]],  t1 = OO[offc[1]];
            f32x2 t2 = OO[offc[2]],  t3 = OO[offc[3]];
#pragma unroll
            for (int l = 4; l < L; l += 4) {
                t0 = t0 * OO[offc[l + 0]];
                t1 = t1 * OO[offc[l + 1]];
                t2 = t2 * OO[offc[l + 2]];
                t3 = t3 * OO[offc[l + 3]];
            }
            TOT[v] = (t0 * t1) * (t2 * t3);
        }
        __syncthreads();

        // ---- fused logratio: r = T/e;
        // log((1+r)/(1-r+1e-9)+1e-9) == log((e+T)/(e-T+1e-9*e)) to ~1e-6
        // (|r| <= tanh(5)^15 ~ 0.9986; t=0 clip(r,+-10) is an identity). ----
#pragma unroll
        for (int l = 0; l < L; ++l) {
            f32x2 Tl = TOT[offt[l]];
            f32x2 e  = ev[l];
            f32x2 num = e + Tl;
            f32x2 den = pk_fma(e, splat(1e-9f), e - Tl);
            f32x2 o;
            o.x = __logf(__fdividef(num.x, den.x));
            o.y = __logf(__fdividef(num.y, den.y));
            ev[l] = o;
        }

        if (t < 4) {
            // ---- odd matvec fully in registers (compile-time weight idx) ----
            const float* __restrict__ wv = oddw_v + (t + 1) * L;
            const float* __restrict__ wm = oddw_e + (t + 1) * (L * L);
            f32x2 s[L];
#pragma unroll
            for (int m = 0; m < L; ++m) s[m] = xv * wv[m];  // uniform s_load
#pragma unroll
            for (int l = 0; l < L; ++l) {
                const f32x2 el = ev[l];
#pragma unroll
                for (int m = 0; m < L; ++m) {
                    if (m != l)                    // diag mask, compile-time
                        s[m] = pk_fma(el, splat(wm[l * L + m]), s[m]);
                }
            }
#pragma unroll
            for (int m = 0; m < L; ++m)
                ev[m] = zsub(tanh_half_clip_pk(s[m]));
        }
    }

    // ---- final: dot with w_e_out straight from registers ----
    {
        f32x2 d = splat(0.0f);
#pragma unroll
        for (int l = 0; l < L; ++l)
            d = pk_fma(ev[l], splat(w_e_out[l]), d);
        if (v < V) {
            const int uA = blk * 2;
            if (MODE == 0) {
                eo_ws[(size_t)uA * V + v]       = d.x;
                eo_ws[(size_t)(uA + 1) * V + v] = d.y;
            } else {
                int ja = invp[pA * (V + 1) + (v + 1)];
                int jb = invp[pB * (V + 1) + (v + 1)];
                atomicAdd(&out[b * (V + 1) + ja], d.x);
                atomicAdd(&out[b * (V + 1) + jb], d.y);
            }
        }
    }
}

// gather-sum epilogue (MODE 0 path)
__global__ __launch_bounds__(256) void out_kernel(
    const float* __restrict__ x,
    const float* __restrict__ eo_ws,
    const int* __restrict__ perma,
    float* __restrict__ out)
{
    const int b = blockIdx.x;
    const int j = threadIdx.x;   // 0..255
    float acc = x[b * (V + 1) + j];
#pragma unroll
    for (int p = 0; p < P; ++p) {
        int idx = perma[p * (V + 1) + j];
        if (idx > 0) acc += eo_ws[((size_t)(b * P + p)) * V + (idx - 1)];
    }
    out[b * (V + 1) + j] = acc;
}

// fallback helpers (MODE 1 path)
__global__ __launch_bounds__(256) void inv_kernel(const int* __restrict__ perma,
                                                  int* __restrict__ invp)
{
    int p = blockIdx.x, j = threadIdx.x;
    invp[p * (V + 1) + perma[p * (V + 1) + j]] = j;
}

__global__ __launch_bounds__(256) void copy_kernel(const float* __restrict__ x,
                                                   float* __restrict__ out, int n)
{
    int i = blockIdx.x * 256 + threadIdx.x;
    if (i < n) out[i] = x[i];
}

extern "C" void kernel_launch(void* const* d_in, const int* in_sizes, int n_in,
                              void* d_out, int out_size, void* d_ws, size_t ws_size,
                              hipStream_t stream)
{
    const float* x       = (const float*)d_in[0];
    const float* oddw_v  = (const float*)d_in[2];
    const float* oddw_e  = (const float*)d_in[3];
    const float* w_e_out = (const float*)d_in[4];
    const int*   perma   = (const int*)d_in[5];
    const int*   rc      = (const int*)d_in[6];
    const int*   cr      = (const int*)d_in[7];
    float* out = (float*)d_out;

    const int Bx = in_sizes[0] / (V + 1);
    const int nunits = Bx * P;
    const int npairs = nunits / 2;
    const size_t need = (size_t)nunits * V * sizeof(float);

    if (ws_size >= need) {
        float* eo = (float*)d_ws;
        hipLaunchKernelGGL((bpd_kernel<0>), dim3(npairs), dim3(256), 0, stream,
                           x, oddw_v, oddw_e, w_e_out, perma, rc, cr,
                           eo, (const int*)nullptr, (float*)nullptr);
        hipLaunchKernelGGL(out_kernel, dim3(Bx), dim3(256), 0, stream,
                           x, eo, perma, out);
    } else {
        // atomic fallback: needs P*(V+1)*4 = 8KB workspace for inverse perm
        int* invp = (int*)d_ws;
        hipLaunchKernelGGL(inv_kernel, dim3(P), dim3(V + 1), 0, stream, perma, invp);
        hipLaunchKernelGGL(copy_kernel, dim3((out_size + 255) / 256), dim3(256), 0, stream,
                           x, out, out_size);
        hipLaunchKernelGGL((bpd_kernel<1>), dim3(npairs), dim3(256), 0, stream,
                           x, oddw_v, oddw_e, w_e_out, perma, rc, cr,
                           (float*)nullptr, invp, out);
    }
}